// Round 3
// baseline (920.753 us; speedup 1.0000x reference)
//
#include <hip/hip_runtime.h>
#include <math.h>

typedef unsigned short u16;
typedef unsigned int u32;
typedef float f32x4 __attribute__((ext_vector_type(4)));
typedef short bfrag __attribute__((ext_vector_type(8)));

#define HS 128

__device__ __forceinline__ float sigf(float x) { return 1.0f / (1.0f + __expf(-x)); }
__device__ __forceinline__ float tanhfast(float x) {
    float e = __expf(2.0f * x);
    return 1.0f - 2.0f / (e + 1.0f);
}
__device__ __forceinline__ u16 f2bf(float f) {
    u32 u = __float_as_uint(f);
    return (u16)((u + 0x7FFFu + ((u >> 16) & 1u)) >> 16);
}
__device__ __forceinline__ float bf2f(u16 h) { return __uint_as_float(((u32)h) << 16); }

// B' value: rows 0-127 emb:[W_iou|W_f|W_f], 128-255 hl:[U_iou|U_f|0], 256-383 hr:[U_iou|0|U_f]
// col layout: i->j, o->128+j, u->256+j, fl->384+j, fr->512+j
__device__ __forceinline__ float bval_int(int k, int col,
    const float* W_iou, const float* W_f, const float* U_iou, const float* U_f)
{
    if (col < 384) {
        if (k < 128) return W_iou[k * 384 + col];
        if (k < 256) return U_iou[(k - 128) * 384 + col];
        return U_iou[(k - 256) * 384 + col];
    } else if (col < 512) {
        int cc = col - 384;
        if (k < 128) return W_f[k * 128 + cc];
        if (k < 256) return U_f[(k - 128) * 128 + cc];
        return 0.0f;
    } else {
        int cc = col - 512;
        if (k < 128) return W_f[k * 128 + cc];
        if (k < 256) return 0.0f;
        return U_f[(k - 256) * 128 + cc];
    }
}

// ---------------- prep: B in per-wave-fragment contiguous layout ----------------
// addr = ((kc*NCFA + cfabs)*2 + half)*512 + l*8 + j   (u16)
// lane l: lr=l&15 -> col' = cfabs*16+lr ; lg=l>>4 -> k = kc*32+lg*8+j
// col' gate-interleaved: wc = col'/(NG*32); g = (col'%(NG*32))>>5; jj = col'&31; j0 = 32wc+jj
#define TOT_INT (12 * 40 * 2 * 512)
#define TOT_LEAF (4 * 24 * 2 * 512)

__global__ __launch_bounds__(256) void prep_kernel(
    const float* __restrict__ W_iou, const float* __restrict__ W_f,
    const float* __restrict__ U_iou, const float* __restrict__ U_f,
    u16* __restrict__ Bint, u16* __restrict__ Bleaf, float* __restrict__ zb)
{
    int idx = blockIdx.x * 256 + threadIdx.x;
    if (idx < TOT_INT) {
        int j = idx & 7, l = (idx >> 3) & 63, half = (idx >> 9) & 1;
        int rest = idx >> 10;
        int cfabs = rest % 40, kc = rest / 40;
        int colp = cfabs * 16 + (l & 15);
        int wc = colp / 160, q = colp - wc * 160;
        int g = q >> 5, j0 = 32 * wc + (q & 31);
        int origcol = (g < 3) ? g * 128 + j0 : ((g == 3) ? 384 + j0 : 512 + j0);
        int k = kc * 32 + (l >> 4) * 8 + j;
        float v = bval_int(k, origcol, W_iou, W_f, U_iou, U_f);
        u16 hi = f2bf(v);
        Bint[idx] = half ? f2bf(v - bf2f(hi)) : hi;
    } else if (idx < TOT_INT + TOT_LEAF) {
        int i2 = idx - TOT_INT;
        int j = i2 & 7, l = (i2 >> 3) & 63, half = (i2 >> 9) & 1;
        int rest = i2 >> 10;
        int cfabs = rest % 24, kc = rest / 24;
        int colp = cfabs * 16 + (l & 15);
        int wc = colp / 96, q = colp - wc * 96;
        int g = q >> 5, j0 = 32 * wc + (q & 31);
        int origcol = g * 128 + j0;
        int k = kc * 32 + (l >> 4) * 8 + j;
        float v = W_iou[k * 384 + origcol];
        u16 hi = f2bf(v);
        Bleaf[i2] = half ? f2bf(v - bf2f(hi)) : hi;
    } else if (idx < TOT_INT + TOT_LEAF + 128) {
        zb[idx - TOT_INT - TOT_LEAF] = 0.0f;
    }
}

// ---------------- fused level GEMM + LSTM cell ----------------
// 512 thr = 8 waves (2 row x 4 col). BM=64, BK=32. Wave tile 32 x (NCF*16).
// A: fp32 in LDS via global_load_lds, triple-buffered 2-ahead, XOR-swizzled segs.
// B: direct global->reg (pre-layouted, coalesced 1KB per fragment load).
// Split-3 bf16: AhBh + AlBh + AhBl.
template<int NKC, int NCFA, int NG, bool INTERNAL>
__global__ __launch_bounds__(512, 2) void gemm_lvl(
    const int* __restrict__ x, const int* __restrict__ mask,
    const float* __restrict__ E, const u16* __restrict__ Bg,
    const float* __restrict__ zb,
    const float* __restrict__ b_iou_x, const float* __restrict__ b_f_x,
    const float* __restrict__ b_iou_h, const float* __restrict__ b_f_h,
    float* __restrict__ h, float* __restrict__ c, int s0, int M)
{
    constexpr int NCF = 2 * NG;
    constexpr int NB = 2 * NCF;   // B loads per iter
    __shared__ __align__(16) float ldsA[3 * 2048];
    const int t = threadIdx.x;
    const int n0 = s0 + blockIdx.x * 64;
    const int lastn = s0 + M;
    const int l = t & 63, wid = t >> 6;
    const int wr = wid >> 2, wc = wid & 3;
    const int lr = l & 15, lg = l >> 4;

    // per-thread staging source precompute (NO loads inside the K-loop)
    const int row = t >> 3;
    const int kof = ((t & 7) ^ (row & 7)) * 4;   // pre-inverse-swizzled logical k-offset
    int ns = n0 + row; if (ns >= lastn) ns = s0;
    const float* Eb = mask[ns] ? (E + (size_t)x[ns] * HS) : zb;
    const float* h1 = INTERNAL ? (h + (size_t)(2 * ns + 1) * HS - 128) : (const float*)0;
    const float* h2 = INTERNAL ? (h + (size_t)(2 * ns + 2) * HS - 256) : (const float*)0;

    auto stageA = [&](int kc, int buf) {
        int k = kc * 32 + kof;
        const float* src = Eb + k;
        if (INTERNAL) {
            if (k >= 128) src = h1 + k;
            if (k >= 256) src = h2 + k;
        }
        __builtin_amdgcn_global_load_lds(
            (const __attribute__((address_space(1))) void*)src,
            (__attribute__((address_space(3))) void*)(ldsA + buf * 2048 + t * 4),
            16, 0, 0);
    };

    f32x4 acc[2][NCF];
    const f32x4 zzz = {0.0f, 0.0f, 0.0f, 0.0f};
#pragma unroll
    for (int rf = 0; rf < 2; ++rf)
#pragma unroll
        for (int cf = 0; cf < NCF; ++cf) acc[rf][cf] = zzz;

    stageA(0, 0);
    stageA(1 < NKC - 1 ? 1 : NKC - 1, 1);

#pragma unroll 1
    for (int kc = 0; kc < NKC; ++kc) {
        // B fragment loads (coalesced 1KB lines, L2-resident)
        bfrag bh[NCF], bl[NCF];
        const u16* bp = Bg + ((size_t)(kc * NCFA + wc * NCF) * 2) * 512 + l * 8;
#pragma unroll
        for (int cf = 0; cf < NCF; ++cf) {
            bh[cf] = *(const bfrag*)(bp + (size_t)cf * 1024);
            bl[cf] = *(const bfrag*)(bp + (size_t)cf * 1024 + 512);
        }
        // A(kc) DMA retired (issued 2 iters ago; NB B-loads + 1 newer DMA outstanding)
        asm volatile("s_waitcnt vmcnt(%0)" :: "i"(NB + 1) : "memory");
        __builtin_amdgcn_s_barrier();
        asm volatile("" ::: "memory");   // fence: no LDS reads / DMA hoist above barrier
        { int kn = kc + 2; if (kn > NKC - 1) kn = NKC - 1; stageA(kn, (kc + 2) % 3); }

        // A fragments: fp32 LDS -> bf16 hi/lo (truncated hi)
        const float* abase = ldsA + (kc % 3) * 2048;
        bfrag ah[2], al[2];
#pragma unroll
        for (int rf = 0; rf < 2; ++rf) {
            int arow = 32 * wr + 16 * rf + lr;
            int rs = lr & 7;
            const float* rbase = abase + arow * 32;
            f32x4 v0 = *(const f32x4*)(rbase + (((2 * lg) ^ rs) << 2));
            f32x4 v1 = *(const f32x4*)(rbase + (((2 * lg + 1) ^ rs) << 2));
            bfrag H, L;
#pragma unroll
            for (int j = 0; j < 4; ++j) {
                u32 u = __float_as_uint(v0[j]);
                u32 hu = u & 0xFFFF0000u;
                H[j] = (short)(hu >> 16);
                L[j] = (short)f2bf(v0[j] - __uint_as_float(hu));
            }
#pragma unroll
            for (int j = 0; j < 4; ++j) {
                u32 u = __float_as_uint(v1[j]);
                u32 hu = u & 0xFFFF0000u;
                H[4 + j] = (short)(hu >> 16);
                L[4 + j] = (short)f2bf(v1[j] - __uint_as_float(hu));
            }
            ah[rf] = H; al[rf] = L;
        }

#pragma unroll
        for (int cf = 0; cf < NCF; ++cf) {
            acc[0][cf] = __builtin_amdgcn_mfma_f32_16x16x32_bf16(ah[0], bh[cf], acc[0][cf], 0, 0, 0);
            acc[1][cf] = __builtin_amdgcn_mfma_f32_16x16x32_bf16(ah[1], bh[cf], acc[1][cf], 0, 0, 0);
            acc[0][cf] = __builtin_amdgcn_mfma_f32_16x16x32_bf16(al[0], bh[cf], acc[0][cf], 0, 0, 0);
            acc[1][cf] = __builtin_amdgcn_mfma_f32_16x16x32_bf16(al[1], bh[cf], acc[1][cf], 0, 0, 0);
            acc[0][cf] = __builtin_amdgcn_mfma_f32_16x16x32_bf16(ah[0], bl[cf], acc[0][cf], 0, 0, 0);
            acc[1][cf] = __builtin_amdgcn_mfma_f32_16x16x32_bf16(ah[1], bl[cf], acc[1][cf], 0, 0, 0);
        }
    }

    // ---- register-local epilogue: lane lr owns column j for ALL gates ----
#pragma unroll
    for (int hi = 0; hi < 2; ++hi) {
        int j = 32 * wc + 16 * hi + lr;
        float bix = b_iou_x[j], box = b_iou_x[HS + j], bux = b_iou_x[2 * HS + j];
        float bih = b_iou_h[j], boh = b_iou_h[HS + j], buh = b_iou_h[2 * HS + j];
        float bfx = 0.0f, bfh = 0.0f;
        if constexpr (INTERNAL) { bfx = b_f_x[j]; bfh = b_f_h[j]; }
#pragma unroll
        for (int rf = 0; rf < 2; ++rf) {
#pragma unroll
            for (int r = 0; r < 4; ++r) {
                int n = n0 + 32 * wr + 16 * rf + 4 * lg + r;
                if (n >= lastn) continue;
                float m = (float)mask[n];
                float iv = acc[rf][0 + hi][r] + m * bix + bih;
                float ov = acc[rf][2 + hi][r] + m * box + boh;
                float uv = acc[rf][4 + hi][r] + m * bux + buh;
                float cn;
                if constexpr (INTERNAL) {
                    float fl = acc[rf][6 + hi][r] + m * bfx + bfh;
                    float fr = acc[rf][8 + hi][r] + m * bfx + bfh;
                    float cl = c[(size_t)(2 * n + 1) * HS + j];
                    float cr = c[(size_t)(2 * n + 2) * HS + j];
                    cn = sigf(iv) * tanhfast(uv) + sigf(fl) * cl + sigf(fr) * cr;
                } else {
                    cn = sigf(iv) * tanhfast(uv);
                }
                float hn = sigf(ov) * tanhfast(cn);
                c[(size_t)n * HS + j] = cn;
                h[(size_t)n * HS + j] = hn;
            }
        }
    }
}

extern "C" void kernel_launch(void* const* d_in, const int* in_sizes, int n_in,
                              void* d_out, int out_size, void* d_ws, size_t ws_size,
                              hipStream_t stream)
{
    const int*   x       = (const int*)d_in[0];
    const int*   mask    = (const int*)d_in[1];
    const float* E       = (const float*)d_in[2];
    const float* W_iou   = (const float*)d_in[3];
    const float* b_iou_x = (const float*)d_in[4];
    const float* W_f     = (const float*)d_in[5];
    const float* b_f_x   = (const float*)d_in[6];
    const float* U_iou   = (const float*)d_in[7];
    const float* b_iou_h = (const float*)d_in[8];
    const float* U_f     = (const float*)d_in[9];
    const float* b_f_h   = (const float*)d_in[10];

    float* h   = (float*)d_out;
    u16* Bint  = (u16*)d_ws;                                    // 983040 B
    u16* Bleaf = (u16*)((char*)d_ws + 983040);                  // 196608 B
    float* zb  = (float*)((char*)d_ws + 1179648);               // 512 B
    float* c   = (float*)((char*)d_ws + 1180160);               // N*128*4 B

    {
        int tot = TOT_INT + TOT_LEAF + 128;
        prep_kernel<<<(tot + 255) / 256, 256, 0, stream>>>(W_iou, W_f, U_iou, U_f, Bint, Bleaf, zb);
    }

    {   // leaves, lvl = 17: K=128 (4 kc), 384 cols (24 cfrags), 3 gates
        int s0 = (1 << 17) - 1, M = 1 << 17;
        gemm_lvl<4, 24, 3, false><<<M / 64, 512, 0, stream>>>(
            x, mask, E, Bleaf, zb, b_iou_x, b_f_x, b_iou_h, b_f_h, h, c, s0, M);
    }
    for (int lvl = 16; lvl >= 0; --lvl) {
        int s0 = (1 << lvl) - 1, M = 1 << lvl;
        int blocks = (M + 63) / 64;
        gemm_lvl<12, 40, 5, true><<<blocks, 512, 0, stream>>>(
            x, mask, E, Bint, zb, b_iou_x, b_f_x, b_iou_h, b_f_h, h, c, s0, M);
    }
}

// Round 5
// 813.139 us; speedup vs baseline: 1.1323x; 1.1323x over previous
//
#include <hip/hip_runtime.h>
#include <math.h>

typedef unsigned short u16;
typedef unsigned int u32;
typedef float f32x4 __attribute__((ext_vector_type(4)));
typedef short bfrag __attribute__((ext_vector_type(8)));

#define HS 128

__device__ __forceinline__ float sigf(float x) { return 1.0f / (1.0f + __expf(-x)); }
__device__ __forceinline__ float tanhfast(float x) {
    float e = __expf(2.0f * x);
    return 1.0f - 2.0f / (e + 1.0f);
}
__device__ __forceinline__ u16 f2bf(float f) {
    u32 u = __float_as_uint(f);
    return (u16)((u + 0x7FFFu + ((u >> 16) & 1u)) >> 16);
}
__device__ __forceinline__ float bf2f(u16 h) { return __uint_as_float(((u32)h) << 16); }

// B' value: rows 0-127 emb:[W_iou|W_f|W_f], 128-255 hl:[U_iou|U_f|0], 256-383 hr:[U_iou|0|U_f]
__device__ __forceinline__ float bval_int(int k, int col,
    const float* W_iou, const float* W_f, const float* U_iou, const float* U_f)
{
    if (col < 384) {
        if (k < 128) return W_iou[k * 384 + col];
        if (k < 256) return U_iou[(k - 128) * 384 + col];
        return U_iou[(k - 256) * 384 + col];
    } else if (col < 512) {
        int cc = col - 384;
        if (k < 128) return W_f[k * 128 + cc];
        if (k < 256) return U_f[(k - 128) * 128 + cc];
        return 0.0f;
    } else {
        int cc = col - 512;
        if (k < 128) return W_f[k * 128 + cc];
        if (k < 256) return 0.0f;
        return U_f[(k - 256) * 128 + cc];
    }
}

// ---------------- prep (round-3 B layout, verbatim) + optional bf16 planes ----------------
#define TOT_INT (12 * 40 * 2 * 512)        // 491520
#define TOT_LEAF (4 * 24 * 2 * 512)        // 98304
#define ZBF_OFF (TOT_INT + TOT_LEAF)       // 589824
#define EPL_OFF (ZBF_OFF + 128)            // 589952
#define TOT_E 4096000
#define ZBP_OFF (EPL_OFF + TOT_E)          // 4685952
#define PREP_ALL (ZBP_OFF + 128)           // 4686080

__global__ __launch_bounds__(256) void prep_kernel(
    const float* __restrict__ W_iou, const float* __restrict__ W_f,
    const float* __restrict__ U_iou, const float* __restrict__ U_f,
    const float* __restrict__ E,
    u16* __restrict__ Bint, u16* __restrict__ Bleaf,
    u16* __restrict__ EH, u16* __restrict__ EL,
    u16* __restrict__ zbp, float* __restrict__ zbf, int do_planes)
{
    int idx = blockIdx.x * 256 + threadIdx.x;
    if (idx < TOT_INT) {
        int j = idx & 7, l = (idx >> 3) & 63, half = (idx >> 9) & 1;
        int rest = idx >> 10;
        int cfabs = rest % 40, kc = rest / 40;
        int colp = cfabs * 16 + (l & 15);
        int wc = colp / 160, q = colp - wc * 160;
        int g = q >> 5, j0 = 32 * wc + (q & 31);
        int origcol = (g < 3) ? g * 128 + j0 : ((g == 3) ? 384 + j0 : 512 + j0);
        int k = kc * 32 + (l >> 4) * 8 + j;
        float v = bval_int(k, origcol, W_iou, W_f, U_iou, U_f);
        u16 hi = f2bf(v);
        Bint[idx] = half ? f2bf(v - bf2f(hi)) : hi;
    } else if (idx < TOT_INT + TOT_LEAF) {
        int i2 = idx - TOT_INT;
        int j = i2 & 7, l = (i2 >> 3) & 63, half = (i2 >> 9) & 1;
        int rest = i2 >> 10;
        int cfabs = rest % 24, kc = rest / 24;
        int colp = cfabs * 16 + (l & 15);
        int wc = colp / 96, q = colp - wc * 96;
        int g = q >> 5, j0 = 32 * wc + (q & 31);
        int origcol = g * 128 + j0;
        int k = kc * 32 + (l >> 4) * 8 + j;
        float v = W_iou[k * 384 + origcol];
        u16 hi = f2bf(v);
        Bleaf[i2] = half ? f2bf(v - bf2f(hi)) : hi;
    } else if (idx < EPL_OFF) {
        zbf[idx - ZBF_OFF] = 0.0f;
    } else if (do_planes) {
        if (idx < ZBP_OFF) {
            int i3 = idx - EPL_OFF;
            float v = E[i3];
            u16 hi = f2bf(v);
            EH[i3] = hi;
            EL[i3] = f2bf(v - bf2f(hi));
        } else if (idx < PREP_ALL) {
            zbp[idx - ZBP_OFF] = 0;
        }
    }
}

// ---------------- fused level GEMM + LSTM cell (round-3 structure) ----------------
// 512 thr = 8 waves (2 row x 4 col). BM=64, BK=32. Wave tile 32 x (NCF*16).
// PLANES: A staged as pre-split bf16 hi/lo planes via global_load_lds (zero VALU in loop).
// else:   A staged fp32 + in-loop hi/lo convert (round-3 exact).
// B: direct global->reg, pre-layouted per-(kc,wc,cf) 1KB lines (round-3 exact).
template<int NKC, int NCFA, int NG, bool INTERNAL, bool PLANES>
__global__ __launch_bounds__(512, 2) void gemm_lvl(
    const int* __restrict__ x, const int* __restrict__ mask,
    const float* __restrict__ E,
    const u16* __restrict__ EH, const u16* __restrict__ EL,
    const u16* __restrict__ zbp, const float* __restrict__ zbf,
    const u16* __restrict__ Bg,
    const float* __restrict__ b_iou_x, const float* __restrict__ b_f_x,
    const float* __restrict__ b_iou_h, const float* __restrict__ b_f_h,
    float* __restrict__ h, float* __restrict__ c,
    u16* __restrict__ hbH, u16* __restrict__ hbL, int s0, int M)
{
    constexpr int NCF = 2 * NG;
    constexpr int NB = 2 * NCF;   // B vmem loads per iter
    __shared__ __align__(16) u16 ldsRaw[3 * 4096];   // 24576 B (same as round 3)
    u16* ldsAp = ldsRaw;
    float* ldsAf = (float*)ldsRaw;
    const int t = threadIdx.x;
    const int n0 = s0 + blockIdx.x * 64;
    const int lastn = s0 + M;
    const int l = t & 63, wid = t >> 6;
    const int wr = wid >> 2, wc = wid & 3;
    const int lr = l & 15, lg = l >> 4;

    // ---- staging source precompute (no loads inside K-loop) ----
    const u16 *ebp = nullptr, *hb1p = nullptr, *hb2p = nullptr;
    const float *Ebf = nullptr, *h1f = nullptr, *h2f = nullptr;
    int fkof = 0;
    if constexpr (PLANES) {
        const int prow = t & 63;
        const int plgs8 = ((t >> 6) & 3) * 8;
        const int pp = t >> 8;
        int ns = n0 + prow; if (ns >= lastn) ns = s0;
        const u16* Ep = pp ? EL : EH;
        ebp = (mask[ns] ? (Ep + (size_t)x[ns] * HS) : zbp) + plgs8;
        if constexpr (INTERNAL) {
            const u16* hbp = pp ? hbL : hbH;
            hb1p = hbp + (size_t)(2 * ns + 1) * HS + plgs8;
            hb2p = hbp + (size_t)(2 * ns + 2) * HS + plgs8;
        }
    } else {
        const int frow = t >> 3;
        fkof = ((t & 7) ^ (frow & 7)) * 4;
        int ns = n0 + frow; if (ns >= lastn) ns = s0;
        Ebf = mask[ns] ? (E + (size_t)x[ns] * HS) : zbf;
        if constexpr (INTERNAL) {
            h1f = h + (size_t)(2 * ns + 1) * HS - 128;
            h2f = h + (size_t)(2 * ns + 2) * HS - 256;
        }
    }

    auto stageA = [&](int kc, int buf) {
        if constexpr (PLANES) {
            const u16* src;
            if constexpr (INTERNAL) {
                int seg = kc >> 2, ks = kc & 3;
                src = (seg == 0 ? ebp : (seg == 1 ? hb1p : hb2p)) + ks * 32;
            } else {
                src = ebp + kc * 32;
            }
            __builtin_amdgcn_global_load_lds(
                (const __attribute__((address_space(1))) void*)src,
                (__attribute__((address_space(3))) void*)(ldsAp + buf * 4096 + t * 8), 16, 0, 0);
        } else {
            int k = kc * 32 + fkof;
            const float* src = Ebf + k;
            if constexpr (INTERNAL) {
                if (k >= 128) src = h1f + k;
                if (k >= 256) src = h2f + k;
            }
            __builtin_amdgcn_global_load_lds(
                (const __attribute__((address_space(1))) void*)src,
                (__attribute__((address_space(3))) void*)(ldsAf + buf * 2048 + t * 4), 16, 0, 0);
        }
    };

    f32x4 acc[2][NCF];
    const f32x4 zzz = {0.0f, 0.0f, 0.0f, 0.0f};
#pragma unroll
    for (int rf = 0; rf < 2; ++rf)
#pragma unroll
        for (int cf = 0; cf < NCF; ++cf) acc[rf][cf] = zzz;

    stageA(0, 0);
    stageA(1 < NKC - 1 ? 1 : NKC - 1, 1);

#pragma unroll 1
    for (int kc = 0; kc < NKC; ++kc) {
        bfrag bh[NCF], bl[NCF];
        const u16* bp = Bg + ((size_t)(kc * NCFA + wc * NCF) * 2) * 512 + l * 8;
#pragma unroll
        for (int cf = 0; cf < NCF; ++cf) {
            bh[cf] = *(const bfrag*)(bp + (size_t)cf * 1024);
            bl[cf] = *(const bfrag*)(bp + (size_t)cf * 1024 + 512);
        }
        // retire A(kc): NB B-loads + 1 newer DMA may stay outstanding (round-3 ledger)
        asm volatile("s_waitcnt vmcnt(%0)" :: "i"(NB + 1) : "memory");
        __builtin_amdgcn_s_barrier();
        asm volatile("" ::: "memory");
        { int kn = kc + 2; if (kn > NKC - 1) kn = NKC - 1; stageA(kn, (kc + 2) % 3); }

        bfrag ah[2], al[2];
        if constexpr (PLANES) {
            const u16* ab = ldsAp + (kc % 3) * 4096;
#pragma unroll
            for (int rf = 0; rf < 2; ++rf) {
                int arow = 32 * wr + 16 * rf + lr;
                ah[rf] = *(const bfrag*)(ab + (lg * 64 + arow) * 8);
                al[rf] = *(const bfrag*)(ab + ((4 + lg) * 64 + arow) * 8);
            }
        } else {
            const float* abase = ldsAf + (kc % 3) * 2048;
#pragma unroll
            for (int rf = 0; rf < 2; ++rf) {
                int arow = 32 * wr + 16 * rf + lr;
                int rs = lr & 7;
                const float* rbase = abase + arow * 32;
                f32x4 v0 = *(const f32x4*)(rbase + (((2 * lg) ^ rs) << 2));
                f32x4 v1 = *(const f32x4*)(rbase + (((2 * lg + 1) ^ rs) << 2));
                bfrag H, L;
#pragma unroll
                for (int j = 0; j < 4; ++j) {
                    u32 u = __float_as_uint(v0[j]);
                    u32 hu = u & 0xFFFF0000u;
                    H[j] = (short)(hu >> 16);
                    L[j] = (short)f2bf(v0[j] - __uint_as_float(hu));
                }
#pragma unroll
                for (int j = 0; j < 4; ++j) {
                    u32 u = __float_as_uint(v1[j]);
                    u32 hu = u & 0xFFFF0000u;
                    H[4 + j] = (short)(hu >> 16);
                    L[4 + j] = (short)f2bf(v1[j] - __uint_as_float(hu));
                }
                ah[rf] = H; al[rf] = L;
            }
        }

#pragma unroll
        for (int cf = 0; cf < NCF; ++cf) {
            acc[0][cf] = __builtin_amdgcn_mfma_f32_16x16x32_bf16(ah[0], bh[cf], acc[0][cf], 0, 0, 0);
            acc[1][cf] = __builtin_amdgcn_mfma_f32_16x16x32_bf16(ah[1], bh[cf], acc[1][cf], 0, 0, 0);
            acc[0][cf] = __builtin_amdgcn_mfma_f32_16x16x32_bf16(al[0], bh[cf], acc[0][cf], 0, 0, 0);
            acc[1][cf] = __builtin_amdgcn_mfma_f32_16x16x32_bf16(al[1], bh[cf], acc[1][cf], 0, 0, 0);
            acc[0][cf] = __builtin_amdgcn_mfma_f32_16x16x32_bf16(ah[0], bl[cf], acc[0][cf], 0, 0, 0);
            acc[1][cf] = __builtin_amdgcn_mfma_f32_16x16x32_bf16(ah[1], bl[cf], acc[1][cf], 0, 0, 0);
        }
    }

    // ---- register-local epilogue (round-3 exact) + optional hb-plane stores ----
#pragma unroll
    for (int hi = 0; hi < 2; ++hi) {
        int j = 32 * wc + 16 * hi + lr;
        float bix = b_iou_x[j], box = b_iou_x[HS + j], bux = b_iou_x[2 * HS + j];
        float bih = b_iou_h[j], boh = b_iou_h[HS + j], buh = b_iou_h[2 * HS + j];
        float bfx = 0.0f, bfh = 0.0f;
        if constexpr (INTERNAL) { bfx = b_f_x[j]; bfh = b_f_h[j]; }
#pragma unroll
        for (int rf = 0; rf < 2; ++rf) {
#pragma unroll
            for (int r = 0; r < 4; ++r) {
                int n = n0 + 32 * wr + 16 * rf + 4 * lg + r;
                if (n >= lastn) continue;
                float m = (float)mask[n];
                float iv = acc[rf][0 + hi][r] + m * bix + bih;
                float ov = acc[rf][2 + hi][r] + m * box + boh;
                float uv = acc[rf][4 + hi][r] + m * bux + buh;
                float cn;
                if constexpr (INTERNAL) {
                    float fl = acc[rf][6 + hi][r] + m * bfx + bfh;
                    float fr = acc[rf][8 + hi][r] + m * bfx + bfh;
                    float cl = c[(size_t)(2 * n + 1) * HS + j];
                    float cr = c[(size_t)(2 * n + 2) * HS + j];
                    cn = sigf(iv) * tanhfast(uv) + sigf(fl) * cl + sigf(fr) * cr;
                } else {
                    cn = sigf(iv) * tanhfast(uv);
                }
                float hn = sigf(ov) * tanhfast(cn);
                c[(size_t)n * HS + j] = cn;
                h[(size_t)n * HS + j] = hn;
                if constexpr (PLANES) {
                    u16 hh = f2bf(hn);
                    hbH[(size_t)n * HS + j] = hh;
                    hbL[(size_t)n * HS + j] = f2bf(hn - bf2f(hh));
                }
            }
        }
    }
}

extern "C" void kernel_launch(void* const* d_in, const int* in_sizes, int n_in,
                              void* d_out, int out_size, void* d_ws, size_t ws_size,
                              hipStream_t stream)
{
    const int*   x       = (const int*)d_in[0];
    const int*   mask    = (const int*)d_in[1];
    const float* E       = (const float*)d_in[2];
    const float* W_iou   = (const float*)d_in[3];
    const float* b_iou_x = (const float*)d_in[4];
    const float* W_f     = (const float*)d_in[5];
    const float* b_f_x   = (const float*)d_in[6];
    const float* U_iou   = (const float*)d_in[7];
    const float* b_iou_h = (const float*)d_in[8];
    const float* U_f     = (const float*)d_in[9];
    const float* b_f_h   = (const float*)d_in[10];

    float* h = (float*)d_out;
    char* ws = (char*)d_ws;

    u16*   Bint  = (u16*)(ws);                      // 983,040
    u16*   Bleaf = (u16*)(ws + 983040);             // 196,608 -> 1,179,648
    float* zbf   = (float*)(ws + 1179648);          // 512     -> 1,180,160

    const size_t NEED = 285998848ull;
    bool planes = ws_size >= NEED;

    if (planes) {
        u16*   EH  = (u16*)(ws + 1180160);           // 8,192,000  -> 9,372,160
        u16*   EL  = (u16*)(ws + 9372160);           // 8,192,000  -> 17,564,160
        u16*   zbp = (u16*)(ws + 17564160);          // 256        -> 17,564,416
        float* c   = (float*)(ws + 17564416);        // 134,217,216 -> 151,781,632
        u16*   hbH = (u16*)(ws + 151781632);         // 67,108,608  -> 218,890,240
        u16*   hbL = (u16*)(ws + 218890240);         // 67,108,608  -> 285,998,848

        prep_kernel<<<PREP_ALL / 256, 256, 0, stream>>>(
            W_iou, W_f, U_iou, U_f, E, Bint, Bleaf, EH, EL, zbp, zbf, 1);

        {   // leaves, lvl = 17: K=128 (4 kc), 384 cols
            int s0 = (1 << 17) - 1, M = 1 << 17;
            gemm_lvl<4, 24, 3, false, true><<<M / 64, 512, 0, stream>>>(
                x, mask, E, EH, EL, zbp, zbf, Bleaf,
                b_iou_x, b_f_x, b_iou_h, b_f_h, h, c, hbH, hbL, s0, M);
        }
        for (int lvl = 16; lvl >= 0; --lvl) {
            int s0 = (1 << lvl) - 1, M = 1 << lvl;
            int blocks = (M + 63) / 64;
            gemm_lvl<12, 40, 5, true, true><<<blocks, 512, 0, stream>>>(
                x, mask, E, EH, EL, zbp, zbf, Bint,
                b_iou_x, b_f_x, b_iou_h, b_f_h, h, c, hbH, hbL, s0, M);
        }
    } else {
        float* c = (float*)(ws + 1180160);
        prep_kernel<<<(EPL_OFF + 255) / 256, 256, 0, stream>>>(
            W_iou, W_f, U_iou, U_f, E, Bint, Bleaf, nullptr, nullptr, nullptr, zbf, 0);

        {   // leaves
            int s0 = (1 << 17) - 1, M = 1 << 17;
            gemm_lvl<4, 24, 3, false, false><<<M / 64, 512, 0, stream>>>(
                x, mask, E, nullptr, nullptr, nullptr, zbf, Bleaf,
                b_iou_x, b_f_x, b_iou_h, b_f_h, h, c, nullptr, nullptr, s0, M);
        }
        for (int lvl = 16; lvl >= 0; --lvl) {
            int s0 = (1 << lvl) - 1, M = 1 << lvl;
            int blocks = (M + 63) / 64;
            gemm_lvl<12, 40, 5, true, false><<<blocks, 512, 0, stream>>>(
                x, mask, E, nullptr, nullptr, nullptr, zbf, Bint,
                b_iou_x, b_f_x, b_iou_h, b_f_h, h, c, nullptr, nullptr, s0, M);
        }
    }
}